// Round 1
// baseline (192.417 us; speedup 1.0000x reference)
//
#include <hip/hip_runtime.h>

// PerturbedTopK: B=128, N=1000, D=196, K=48, sigma=0.05
//
// Per (b,n) row: exact top-K of x[b,:] + sigma*noise[b,n,:], tie-break lowest
// index first (jax.lax.top_k), then scatter 1/N at (b, rank_by_index, d).
//
// Strategy:
//  - one wave per row; lane l owns d = 4l..4l+3 via one float4 load (49 lanes
//    active; 49*16B = 784B = exactly one row, every row 16B-aligned).
//  - monotonic float->uint key transform; exact threshold T found by:
//      pivot = exact 48th-largest key of x[b] (32-iter bit search, once/wave,
//      amortized over ~31 rows), then c = #{key > pivot} and |c-48|+1 exact
//      min/max extraction levels (wave shfl_xor reduce). Correctness does not
//      depend on pivot quality - it only sets the number of extraction levels.
//  - selection + rank-by-index via ballot + mbcnt prefix counts (exact ties).
//  - per-block LDS counters, 2 x u16 packed per u32 (18.8KB -> 8 blocks/CU),
//    sparse atomicAdd(count/N) flush into zeroed d_out.

#define BB 128
#define NN 1000
#define DD 196
#define KK 48

constexpr int SPLIT   = 8;            // blocks per b (n-range split)
constexpr int ROWS    = NN / SPLIT;   // 125 rows per block
constexpr int THREADS = 256;          // 4 waves
constexpr int NWAVES  = THREADS / 64;
constexpr int DH      = DD / 2;       // 98 packed columns
constexpr int LDSN    = KK * DH;      // 4704 u32

__device__ __forceinline__ unsigned key_of(float v) {
  // monotonic: a < b  <=>  key_of(a) < key_of(b) (unsigned)
  unsigned u = __float_as_uint(v);
  return u ^ (0x80000000u | (unsigned)((int)u >> 31));
}

__device__ __forceinline__ int mbcnt64(unsigned long long m) {
  // popcount(m & lanemask_lt)
  return __builtin_amdgcn_mbcnt_hi((unsigned)(m >> 32),
         __builtin_amdgcn_mbcnt_lo((unsigned)m, 0));
}

__global__ __launch_bounds__(THREADS) void ptopk_kernel(
    const float* __restrict__ x, const float* __restrict__ noise,
    const float* __restrict__ sigp, float* __restrict__ out) {
  __shared__ unsigned cnt[LDSN];
  const int tid   = threadIdx.x;
  const int b     = blockIdx.x / SPLIT;
  const int split = blockIdx.x % SPLIT;

  for (int i = tid; i < LDSN; i += THREADS) cnt[i] = 0u;
  __syncthreads();

  const float sigma = sigp[0];
  const int lane = tid & 63;
  const int wv   = tid >> 6;
  const bool lv  = lane < 49;  // 49 lanes * 4 floats = 196 = D

  float4 xv = make_float4(0.f, 0.f, 0.f, 0.f);
  if (lv) xv = *reinterpret_cast<const float4*>(x + b * DD + 4 * lane);
  unsigned xk0 = lv ? key_of(xv.x) : 0u;
  unsigned xk1 = lv ? key_of(xv.y) : 0u;
  unsigned xk2 = lv ? key_of(xv.z) : 0u;
  unsigned xk3 = lv ? key_of(xv.w) : 0u;

  // pivot = exact 48th-largest key of x[b] (runs once per wave)
  unsigned piv = 0u;
  #pragma unroll
  for (int bit = 31; bit >= 0; --bit) {
    unsigned cand = piv | (1u << bit);
    int c = __popcll(__ballot(xk0 >= cand)) + __popcll(__ballot(xk1 >= cand))
          + __popcll(__ballot(xk2 >= cand)) + __popcll(__ballot(xk3 >= cand));
    if (c >= KK) piv = cand;
  }

  const float* nbase = noise + ((size_t)b * NN + (size_t)split * ROWS) * DD;

  for (int r = wv; r < ROWS; r += NWAVES) {
    float4 nv = make_float4(0.f, 0.f, 0.f, 0.f);
    if (lv) nv = *reinterpret_cast<const float4*>(nbase + (size_t)r * DD + 4 * lane);
    const unsigned k0 = lv ? key_of(fmaf(sigma, nv.x, xv.x)) : 0u;
    const unsigned k1 = lv ? key_of(fmaf(sigma, nv.y, xv.y)) : 0u;
    const unsigned k2 = lv ? key_of(fmaf(sigma, nv.z, xv.z)) : 0u;
    const unsigned k3 = lv ? key_of(fmaf(sigma, nv.w, xv.w)) : 0u;

    // c = #{key > pivot}; typically 48 +/- 2 because sigma is small
    const int c = __popcll(__ballot(k0 > piv)) + __popcll(__ballot(k1 > piv))
                + __popcll(__ballot(k2 > piv)) + __popcll(__ballot(k3 > piv));

    unsigned T = 0u;  // exact 48th-largest perturbed key
    if (c >= KK) {
      // T = (c-47)-th smallest element of S = {key > piv}
      int rem = c - (KK - 1);
      unsigned m0 = (k0 > piv) ? k0 : 0xFFFFFFFFu;
      unsigned m1 = (k1 > piv) ? k1 : 0xFFFFFFFFu;
      unsigned m2 = (k2 > piv) ? k2 : 0xFFFFFFFFu;
      unsigned m3 = (k3 > piv) ? k3 : 0xFFFFFFFFu;
      for (;;) {
        unsigned mm = min(min(m0, m1), min(m2, m3));
        #pragma unroll
        for (int off = 32; off >= 1; off >>= 1)
          mm = min(mm, (unsigned)__shfl_xor((int)mm, off, 64));
        int cv = __popcll(__ballot(m0 == mm)) + __popcll(__ballot(m1 == mm))
               + __popcll(__ballot(m2 == mm)) + __popcll(__ballot(m3 == mm));
        if (cv >= rem) { T = mm; break; }
        rem -= cv;
        m0 = (m0 == mm) ? 0xFFFFFFFFu : m0;
        m1 = (m1 == mm) ? 0xFFFFFFFFu : m1;
        m2 = (m2 == mm) ? 0xFFFFFFFFu : m2;
        m3 = (m3 == mm) ? 0xFFFFFFFFu : m3;
      }
    } else {
      // T = (48-c)-th largest element of U = {key <= piv}
      int rem = KK - c;
      unsigned m0 = (k0 <= piv) ? k0 : 0u;
      unsigned m1 = (k1 <= piv) ? k1 : 0u;
      unsigned m2 = (k2 <= piv) ? k2 : 0u;
      unsigned m3 = (k3 <= piv) ? k3 : 0u;
      for (;;) {
        unsigned mm = max(max(m0, m1), max(m2, m3));
        #pragma unroll
        for (int off = 32; off >= 1; off >>= 1)
          mm = max(mm, (unsigned)__shfl_xor((int)mm, off, 64));
        int cv = __popcll(__ballot(m0 == mm)) + __popcll(__ballot(m1 == mm))
               + __popcll(__ballot(m2 == mm)) + __popcll(__ballot(m3 == mm));
        if (cv >= rem) { T = mm; break; }
        rem -= cv;
        m0 = (m0 == mm) ? 0u : m0;
        m1 = (m1 == mm) ? 0u : m1;
        m2 = (m2 == mm) ? 0u : m2;
        m3 = (m3 == mm) ? 0u : m3;
      }
    }

    // selection: all > T, plus ties == T by ascending d until budget
    const unsigned long long e0 = __ballot(k0 == T), e1 = __ballot(k1 == T),
                             e2 = __ballot(k2 == T), e3 = __ballot(k3 == T);
    const int cnt_gt = __popcll(__ballot(k0 > T)) + __popcll(__ballot(k1 > T))
                     + __popcll(__ballot(k2 > T)) + __popcll(__ballot(k3 > T));
    const int budget = KK - cnt_gt;
    const bool eq0 = (k0 == T), eq1 = (k1 == T), eq2 = (k2 == T), eq3 = (k3 == T);
    int tr = mbcnt64(e0) + mbcnt64(e1) + mbcnt64(e2) + mbcnt64(e3);
    const bool s0 = (k0 > T) || (eq0 && tr < budget); tr += eq0 ? 1 : 0;
    const bool s1 = (k1 > T) || (eq1 && tr < budget); tr += eq1 ? 1 : 0;
    const bool s2 = (k2 > T) || (eq2 && tr < budget); tr += eq2 ? 1 : 0;
    const bool s3 = (k3 > T) || (eq3 && tr < budget);

    // rank-by-index = prefix count of selected below d (d = 4*lane + s)
    const unsigned long long S0 = __ballot(s0), S1 = __ballot(s1),
                             S2 = __ballot(s2), S3 = __ballot(s3);
    int kp = mbcnt64(S0) + mbcnt64(S1) + mbcnt64(S2) + mbcnt64(S3);
    const int b2 = 2 * lane;  // packed column for d=4l..4l+1 is 2l, d=4l+2..3 is 2l+1
    if (s0) atomicAdd(&cnt[kp * DH + b2],     1u);        kp += s0 ? 1 : 0;
    if (s1) atomicAdd(&cnt[kp * DH + b2],     0x10000u);  kp += s1 ? 1 : 0;
    if (s2) atomicAdd(&cnt[kp * DH + b2 + 1], 1u);        kp += s2 ? 1 : 0;
    if (s3) atomicAdd(&cnt[kp * DH + b2 + 1], 0x10000u);
  }

  __syncthreads();

  // sparse flush: count * (1/N) into zero-initialized out (8 partials/loc max)
  const float invn = 1.0f / (float)NN;
  float* ob = out + (size_t)b * KK * DD;
  for (int i = tid; i < LDSN; i += THREADS) {
    const unsigned cv = cnt[i];
    if (cv) {
      const int k   = i / DH;
      const int dd2 = i - k * DH;
      const unsigned lo = cv & 0xFFFFu, hi = cv >> 16;
      float* p = ob + k * DD + 2 * dd2;
      if (lo) atomicAdd(p,     (float)lo * invn);
      if (hi) atomicAdd(p + 1, (float)hi * invn);
    }
  }
}

extern "C" void kernel_launch(void* const* d_in, const int* in_sizes, int n_in,
                              void* d_out, int out_size, void* d_ws, size_t ws_size,
                              hipStream_t stream) {
  (void)in_sizes; (void)n_in; (void)d_ws; (void)ws_size;
  const float* x     = (const float*)d_in[0];
  const float* noise = (const float*)d_in[1];
  const float* sig   = (const float*)d_in[2];
  float* out = (float*)d_out;

  hipMemsetAsync(d_out, 0, (size_t)out_size * sizeof(float), stream);
  ptopk_kernel<<<dim3(BB * SPLIT), dim3(THREADS), 0, stream>>>(x, noise, sig, out);
}

// Round 3
// 168.806 us; speedup vs baseline: 1.1399x; 1.1399x over previous
//
#include <hip/hip_runtime.h>

// PerturbedTopK: B=128, N=1000, D=196, K=48, sigma=0.05
//
// Per (b,n) row: exact top-K of x[b,:] + sigma*noise[b,n,:], tie-break lowest
// index first (jax.lax.top_k), then scatter 1/N at (b, rank_by_index, d).
//
// R2/R3 (R2 never ran - GPU acquisition timeout; identical resubmit):
//  vs R1 (81us, Occ 33%, VALUBusy 33% -> latency-bound):
//  - 512-thread blocks (8 waves): 1024 blocks x 8 = 8192 waves = 32/CU (100%).
//  - pivot[b] precomputed by a tiny kernel into d_ws (was: 32-step ballot
//    search repeated in every wave, ~9us of SALU).
//  - extraction min/max-reduce: 5x ds_swizzle (xor 1..16) + 2x readlane +
//    scalar min/max (was: 6x __shfl_xor -> ds_bpermute chain). T is uniform
//    (SGPR) so all following compares are v_cmp with scalar operand.
//  - next-row float4 software prefetch.

#define BB 128
#define NN 1000
#define DD 196
#define KK 48

constexpr int SPLIT   = 8;            // blocks per b (n-range split)
constexpr int ROWS    = NN / SPLIT;   // 125 rows per block
constexpr int THREADS = 512;          // 8 waves
constexpr int NWAVES  = THREADS / 64;
constexpr int DH      = DD / 2;       // 98 packed columns
constexpr int LDSN    = KK * DH;      // 4704 u32

__device__ __forceinline__ unsigned key_of(float v) {
  // monotonic: a < b  <=>  key_of(a) < key_of(b) (unsigned)
  unsigned u = __float_as_uint(v);
  return u ^ (0x80000000u | (unsigned)((int)u >> 31));
}

__device__ __forceinline__ int mbcnt64(unsigned long long m) {
  return __builtin_amdgcn_mbcnt_hi((unsigned)(m >> 32),
         __builtin_amdgcn_mbcnt_lo((unsigned)m, 0));
}

// min over 64 lanes -> wave-uniform scalar. 5 ds_swizzle xor-levels within
// 32-lane groups, then readlane(0)/readlane(32) + scalar min.
__device__ __forceinline__ unsigned wave_min_u32(unsigned m) {
  unsigned mm = m;
  mm = min(mm, (unsigned)__builtin_amdgcn_ds_swizzle((int)mm, 0x041F)); // ^1
  mm = min(mm, (unsigned)__builtin_amdgcn_ds_swizzle((int)mm, 0x081F)); // ^2
  mm = min(mm, (unsigned)__builtin_amdgcn_ds_swizzle((int)mm, 0x101F)); // ^4
  mm = min(mm, (unsigned)__builtin_amdgcn_ds_swizzle((int)mm, 0x201F)); // ^8
  mm = min(mm, (unsigned)__builtin_amdgcn_ds_swizzle((int)mm, 0x401F)); // ^16
  unsigned a = (unsigned)__builtin_amdgcn_readlane((int)mm, 0);
  unsigned b = (unsigned)__builtin_amdgcn_readlane((int)mm, 32);
  return min(a, b);
}

__device__ __forceinline__ unsigned wave_max_u32(unsigned m) {
  unsigned mm = m;
  mm = max(mm, (unsigned)__builtin_amdgcn_ds_swizzle((int)mm, 0x041F));
  mm = max(mm, (unsigned)__builtin_amdgcn_ds_swizzle((int)mm, 0x081F));
  mm = max(mm, (unsigned)__builtin_amdgcn_ds_swizzle((int)mm, 0x101F));
  mm = max(mm, (unsigned)__builtin_amdgcn_ds_swizzle((int)mm, 0x201F));
  mm = max(mm, (unsigned)__builtin_amdgcn_ds_swizzle((int)mm, 0x401F));
  unsigned a = (unsigned)__builtin_amdgcn_readlane((int)mm, 0);
  unsigned b = (unsigned)__builtin_amdgcn_readlane((int)mm, 32);
  return max(a, b);
}

// piv[b] = exact 48th-largest key of x[b]; one wave per b.
__global__ __launch_bounds__(64) void pivot_kernel(
    const float* __restrict__ x, unsigned* __restrict__ piv) {
  const int b    = blockIdx.x;
  const int lane = threadIdx.x;
  const bool lv  = lane < 49;
  float4 xv = make_float4(0.f, 0.f, 0.f, 0.f);
  if (lv) xv = *reinterpret_cast<const float4*>(x + b * DD + 4 * lane);
  unsigned xk0 = lv ? key_of(xv.x) : 0u;
  unsigned xk1 = lv ? key_of(xv.y) : 0u;
  unsigned xk2 = lv ? key_of(xv.z) : 0u;
  unsigned xk3 = lv ? key_of(xv.w) : 0u;
  unsigned p = 0u;
  #pragma unroll
  for (int bit = 31; bit >= 0; --bit) {
    unsigned cand = p | (1u << bit);
    int c = __popcll(__ballot(xk0 >= cand)) + __popcll(__ballot(xk1 >= cand))
          + __popcll(__ballot(xk2 >= cand)) + __popcll(__ballot(xk3 >= cand));
    if (c >= KK) p = cand;
  }
  if (lane == 0) piv[b] = p;
}

__global__ __launch_bounds__(THREADS) void ptopk_kernel(
    const float* __restrict__ x, const float* __restrict__ noise,
    const float* __restrict__ sigp, const unsigned* __restrict__ pivp,
    float* __restrict__ out) {
  __shared__ unsigned cnt[LDSN];
  const int tid   = threadIdx.x;
  const int b     = blockIdx.x / SPLIT;
  const int split = blockIdx.x % SPLIT;

  for (int i = tid; i < LDSN; i += THREADS) cnt[i] = 0u;
  __syncthreads();

  const float sigma  = sigp[0];
  const unsigned piv = pivp[b];
  const int lane = tid & 63;
  const int wv   = tid >> 6;
  const bool lv  = lane < 49;  // 49 lanes * 4 floats = 196 = D

  float4 xv = make_float4(0.f, 0.f, 0.f, 0.f);
  if (lv) xv = *reinterpret_cast<const float4*>(x + b * DD + 4 * lane);

  const float* nbase = noise + ((size_t)b * NN + (size_t)split * ROWS) * DD;

  // prefetched next-row noise
  float4 nv = make_float4(0.f, 0.f, 0.f, 0.f);
  if (lv && wv < ROWS)
    nv = *reinterpret_cast<const float4*>(nbase + (size_t)wv * DD + 4 * lane);

  for (int r = wv; r < ROWS; r += NWAVES) {
    const float4 cur = nv;
    if (lv && (r + NWAVES) < ROWS)
      nv = *reinterpret_cast<const float4*>(nbase + (size_t)(r + NWAVES) * DD + 4 * lane);

    const unsigned k0 = lv ? key_of(fmaf(sigma, cur.x, xv.x)) : 0u;
    const unsigned k1 = lv ? key_of(fmaf(sigma, cur.y, xv.y)) : 0u;
    const unsigned k2 = lv ? key_of(fmaf(sigma, cur.z, xv.z)) : 0u;
    const unsigned k3 = lv ? key_of(fmaf(sigma, cur.w, xv.w)) : 0u;

    // c = #{key > pivot}; typically 48 +/- a few because sigma is small
    const int c = __popcll(__ballot(k0 > piv)) + __popcll(__ballot(k1 > piv))
                + __popcll(__ballot(k2 > piv)) + __popcll(__ballot(k3 > piv));

    unsigned T = 0u;  // exact 48th-largest perturbed key
    if (c >= KK) {
      // T = (c-47)-th smallest element of S = {key > piv}
      int rem = c - (KK - 1);
      unsigned m0 = (k0 > piv) ? k0 : 0xFFFFFFFFu;
      unsigned m1 = (k1 > piv) ? k1 : 0xFFFFFFFFu;
      unsigned m2 = (k2 > piv) ? k2 : 0xFFFFFFFFu;
      unsigned m3 = (k3 > piv) ? k3 : 0xFFFFFFFFu;
      for (;;) {
        const unsigned mm = wave_min_u32(min(min(m0, m1), min(m2, m3)));
        int cv = __popcll(__ballot(m0 == mm)) + __popcll(__ballot(m1 == mm))
               + __popcll(__ballot(m2 == mm)) + __popcll(__ballot(m3 == mm));
        if (cv >= rem) { T = mm; break; }
        rem -= cv;
        m0 = (m0 == mm) ? 0xFFFFFFFFu : m0;
        m1 = (m1 == mm) ? 0xFFFFFFFFu : m1;
        m2 = (m2 == mm) ? 0xFFFFFFFFu : m2;
        m3 = (m3 == mm) ? 0xFFFFFFFFu : m3;
      }
    } else {
      // T = (48-c)-th largest element of U = {key <= piv}
      int rem = KK - c;
      unsigned m0 = (k0 <= piv) ? k0 : 0u;
      unsigned m1 = (k1 <= piv) ? k1 : 0u;
      unsigned m2 = (k2 <= piv) ? k2 : 0u;
      unsigned m3 = (k3 <= piv) ? k3 : 0u;
      for (;;) {
        const unsigned mm = wave_max_u32(max(max(m0, m1), max(m2, m3)));
        int cv = __popcll(__ballot(m0 == mm)) + __popcll(__ballot(m1 == mm))
               + __popcll(__ballot(m2 == mm)) + __popcll(__ballot(m3 == mm));
        if (cv >= rem) { T = mm; break; }
        rem -= cv;
        m0 = (m0 == mm) ? 0u : m0;
        m1 = (m1 == mm) ? 0u : m1;
        m2 = (m2 == mm) ? 0u : m2;
        m3 = (m3 == mm) ? 0u : m3;
      }
    }

    // selection: all > T, plus ties == T by ascending d until budget
    const unsigned long long e0 = __ballot(k0 == T), e1 = __ballot(k1 == T),
                             e2 = __ballot(k2 == T), e3 = __ballot(k3 == T);
    const int cnt_gt = __popcll(__ballot(k0 > T)) + __popcll(__ballot(k1 > T))
                     + __popcll(__ballot(k2 > T)) + __popcll(__ballot(k3 > T));
    const int budget = KK - cnt_gt;
    const bool eq0 = (k0 == T), eq1 = (k1 == T), eq2 = (k2 == T), eq3 = (k3 == T);
    int tr = mbcnt64(e0) + mbcnt64(e1) + mbcnt64(e2) + mbcnt64(e3);
    const bool s0 = (k0 > T) || (eq0 && tr < budget); tr += eq0 ? 1 : 0;
    const bool s1 = (k1 > T) || (eq1 && tr < budget); tr += eq1 ? 1 : 0;
    const bool s2 = (k2 > T) || (eq2 && tr < budget); tr += eq2 ? 1 : 0;
    const bool s3 = (k3 > T) || (eq3 && tr < budget);

    // rank-by-index k = prefix count of selected below d (d = 4*lane + s)
    const unsigned long long S0 = __ballot(s0), S1 = __ballot(s1),
                             S2 = __ballot(s2), S3 = __ballot(s3);
    int kp = mbcnt64(S0) + mbcnt64(S1) + mbcnt64(S2) + mbcnt64(S3);
    const int b2 = 2 * lane;  // packed col: d=4l..4l+1 -> 2l, d=4l+2..3 -> 2l+1
    if (s0) atomicAdd(&cnt[kp * DH + b2],     1u);        kp += s0 ? 1 : 0;
    if (s1) atomicAdd(&cnt[kp * DH + b2],     0x10000u);  kp += s1 ? 1 : 0;
    if (s2) atomicAdd(&cnt[kp * DH + b2 + 1], 1u);        kp += s2 ? 1 : 0;
    if (s3) atomicAdd(&cnt[kp * DH + b2 + 1], 0x10000u);
  }

  __syncthreads();

  // sparse flush: count * (1/N) into zero-initialized out
  const float invn = 1.0f / (float)NN;
  float* ob = out + (size_t)b * KK * DD;
  for (int i = tid; i < LDSN; i += THREADS) {
    const unsigned cv = cnt[i];
    if (cv) {
      const int k   = i / DH;
      const int dd2 = i - k * DH;
      const unsigned lo = cv & 0xFFFFu, hi = cv >> 16;
      float* p = ob + k * DD + 2 * dd2;
      if (lo) atomicAdd(p,     (float)lo * invn);
      if (hi) atomicAdd(p + 1, (float)hi * invn);
    }
  }
}

extern "C" void kernel_launch(void* const* d_in, const int* in_sizes, int n_in,
                              void* d_out, int out_size, void* d_ws, size_t ws_size,
                              hipStream_t stream) {
  (void)in_sizes; (void)n_in; (void)ws_size;
  const float* x     = (const float*)d_in[0];
  const float* noise = (const float*)d_in[1];
  const float* sig   = (const float*)d_in[2];
  float* out = (float*)d_out;
  unsigned* piv = (unsigned*)d_ws;

  hipMemsetAsync(d_out, 0, (size_t)out_size * sizeof(float), stream);
  pivot_kernel<<<dim3(BB), dim3(64), 0, stream>>>(x, piv);
  ptopk_kernel<<<dim3(BB * SPLIT), dim3(THREADS), 0, stream>>>(x, noise, sig, piv, out);
}